// Round 7
// baseline (358.193 us; speedup 1.0000x reference)
//
#include <hip/hip_runtime.h>
#include <hip/hip_bf16.h>

// Problem: B=4, L=2048, E=1024, H=16, HD=64.
// reshape(B,H,L,HD) is a pure reinterpretation of the flat (B,L,E) buffer.
namespace {
constexpr int kB = 4, kL = 2048, kE = 1024, kH = 16, kHD = 64;
constexpr float kCs = 0.18033688f;  // log2(e)/8, folded into Q projection
}

typedef __attribute__((ext_vector_type(8))) short bf16x8;
typedef __attribute__((ext_vector_type(4))) float f32x4;

__device__ __forceinline__ short f2bf(float f) {
  __hip_bfloat16 h = __float2bfloat16(f);
  return *reinterpret_cast<short*>(&h);
}

__device__ __forceinline__ void load_lds16(const void* g, void* l) {
  __builtin_amdgcn_global_load_lds((const __attribute__((address_space(1))) void*)g,
                                   (__attribute__((address_space(3))) void*)l, 16, 0, 0);
}
__device__ __forceinline__ void load_lds4(const void* g, void* l) {
  __builtin_amdgcn_global_load_lds((const __attribute__((address_space(1))) void*)g,
                                   (__attribute__((address_space(3))) void*)l, 4, 0, 0);
}

// fp32 -> bf16 cast, 4 elems/thread
__global__ __launch_bounds__(256) void k_cvt(const float* __restrict__ s,
                                             short* __restrict__ d, int n) {
  int i = (blockIdx.x * 256 + threadIdx.x) * 4;
  if (i < n) {
    float4 v = *reinterpret_cast<const float4*>(s + i);
    short4 o;
    o.x = f2bf(v.x); o.y = f2bf(v.y); o.z = f2bf(v.z); o.w = f2bf(v.w);
    *reinterpret_cast<short4*>(d + i) = o;
  }
}

// 4 weight casts + mask->float-offset precompute, one dispatch.
__global__ __launch_bounds__(256) void k_cvtw(const float* __restrict__ w0,
                                              const float* __restrict__ w1,
                                              const float* __restrict__ w2,
                                              const float* __restrict__ w3,
                                              const int* __restrict__ mask,
                                              short* __restrict__ dst,
                                              float* __restrict__ mkf) {
  int bx = blockIdx.x;
  if (bx >= 4096) {  // mask segment: 8192 elems
    int i = (bx - 4096) * 256 + threadIdx.x;
    mkf[i] = mask[i] != 0 ? -10.0f : -1.0e10f;
    return;
  }
  int seg = bx >> 10;
  const float* s = seg == 0 ? w0 : seg == 1 ? w1 : seg == 2 ? w2 : w3;
  int local = ((bx & 1023) * 256 + threadIdx.x) * 4;
  float4 v = *reinterpret_cast<const float4*>(s + local);
  short4 o;
  o.x = f2bf(v.x); o.y = f2bf(v.y); o.z = f2bf(v.z); o.w = f2bf(v.w);
  *reinterpret_cast<short4*>(dst + seg * 1048576 + local) = o;
}

// Per-head V transpose: Vl[hb][l][d] -> Vt[hb][d][l]. 64x64 tiles via LDS,
// both global sides coalesced.
__global__ __launch_bounds__(256) void k_trv(const short* __restrict__ Vl,
                                             short* __restrict__ Vt) {
  __shared__ unsigned T[64 * 33];
  const int t = threadIdx.x;
  const int hb = blockIdx.y;
  const int l0 = blockIdx.x * 64;
  const short* src = Vl + hb * 131072;
  short* dst = Vt + hb * 131072;
  const int d8 = (t & 7) * 8;
  const int lp = t >> 3;
  const uint4 va = *reinterpret_cast<const uint4*>(src + (l0 + 2 * lp) * 64 + d8);
  const uint4 vb = *reinterpret_cast<const uint4*>(src + (l0 + 2 * lp + 1) * 64 + d8);
  const unsigned a[4] = {va.x, va.y, va.z, va.w};
  const unsigned b[4] = {vb.x, vb.y, vb.z, vb.w};
#pragma unroll
  for (int j = 0; j < 4; ++j) {
    unsigned z0 = __builtin_amdgcn_perm(b[j], a[j], 0x05040100u);
    unsigned z1 = __builtin_amdgcn_perm(b[j], a[j], 0x07060302u);
    T[(d8 + 2 * j) * 33 + lp] = z0;
    T[(d8 + 2 * j + 1) * 33 + lp] = z1;
  }
  __syncthreads();
  const int u = (t & 7) * 4;
#pragma unroll
  for (int h2 = 0; h2 < 2; ++h2) {
    int d = (t >> 3) + h2 * 32;
    uint4 r;
    r.x = T[d * 33 + u];     r.y = T[d * 33 + u + 1];
    r.z = T[d * 33 + u + 2]; r.w = T[d * 33 + u + 3];
    *reinterpret_cast<uint4*>(dst + d * 2048 + l0 + u * 2) = r;
  }
}

// ---- shared GEMM core: 128x128 tile, BK=64, NT, k-major chunk-plane LDS ----
// R6: BK 32->64. Per K-iter: 8 DMA loads + 32 MFMAs per barrier pair instead
// of 4+16 — halves the number of vmcnt(0) barrier-drain events, which R5's
// counters showed consume ~75% of each iteration (MfmaUtil 18%, all pipes
// idle). LDS 16->32 KB (still clear of the m132 64KB occupancy cliff).
struct GemmCore {
  f32x4 acc[4][4];
  int tid, w, lane, quad, m16, wm, wn, r0, kc0;
  __device__ __forceinline__ void run(const short* __restrict__ A,
                                      const short* __restrict__ W,
                                      int bm0, int bn0, short* As, short* Bs) {
    const int K = 1024;
    tid = threadIdx.x;
    w = tid >> 6; lane = tid & 63; quad = lane >> 4; m16 = lane & 15;
    wm = (w >> 1) * 64; wn = (w & 1) * 64;
    r0 = tid & 127; kc0 = tid >> 7;
#pragma unroll
    for (int i = 0; i < 4; ++i)
#pragma unroll
      for (int j = 0; j < 4; ++j) acc[i][j] = (f32x4){0, 0, 0, 0};
    const short* Arow = A + (bm0 + r0) * K + kc0 * 8;
    const short* Wrow = W + (bn0 + r0) * K + kc0 * 8;
    for (int kt = 0; kt < K; kt += 64) {
      // load t stages chunk pair (2t, 2t+1): 4 KB at LDS offset t*2048 shorts
#pragma unroll
      for (int t = 0; t < 4; ++t) {
        load_lds16(Arow + kt + t * 16, &As[t * 2048 + tid * 8]);
        load_lds16(Wrow + kt + t * 16, &Bs[t * 2048 + tid * 8]);
      }
      __syncthreads();
#pragma unroll
      for (int ks = 0; ks < 2; ++ks) {
        bf16x8 a[4], b[4];
#pragma unroll
        for (int i = 0; i < 4; ++i)
          a[i] = *reinterpret_cast<const bf16x8*>(
              &As[(ks * 4 + quad) * 1024 + (wm + i * 16 + m16) * 8]);
#pragma unroll
        for (int j = 0; j < 4; ++j)
          b[j] = *reinterpret_cast<const bf16x8*>(
              &Bs[(ks * 4 + quad) * 1024 + (wn + j * 16 + m16) * 8]);
#pragma unroll
        for (int i = 0; i < 4; ++i)
#pragma unroll
          for (int j = 0; j < 4; ++j)
            acc[i][j] = __builtin_amdgcn_mfma_f32_16x16x32_bf16(a[i], b[j], acc[i][j], 0, 0, 0);
      }
      __syncthreads();
    }
  }
};

// Fused Q/K/V projection: grid.x = 24 (8 col-blocks x 3 outputs).
__global__ __launch_bounds__(256) void k_gemm_qkv(const short* __restrict__ xb,
                                                  const short* __restrict__ Wq,
                                                  const short* __restrict__ Wk,
                                                  const short* __restrict__ Wv,
                                                  const float* __restrict__ bq,
                                                  const float* __restrict__ bk,
                                                  const float* __restrict__ bv,
                                                  short* __restrict__ Q,
                                                  short* __restrict__ K,
                                                  short* __restrict__ Vl) {
  __shared__ short As[8192];
  __shared__ short Bs[8192];
  const int sel = blockIdx.x >> 3;
  const int bn0 = (blockIdx.x & 7) * 128, bm0 = blockIdx.y * 128;
  const short* W = sel == 0 ? Wq : sel == 1 ? Wk : Wv;
  const float* bias = sel == 0 ? bq : sel == 1 ? bk : bv;

  GemmCore g;
  g.run(xb, W, bm0, bn0, As, Bs);

  float bj[4];
#pragma unroll
  for (int j = 0; j < 4; ++j) bj[j] = bias[bn0 + g.wn + j * 16 + g.m16];

  short* C = sel == 0 ? Q : sel == 1 ? K : Vl;
  float sc = sel == 0 ? kCs : 1.0f;
#pragma unroll
  for (int i = 0; i < 4; ++i)
#pragma unroll
    for (int j = 0; j < 4; ++j)
#pragma unroll
      for (int rg = 0; rg < 4; ++rg) {
        int row = bm0 + g.wm + i * 16 + g.quad * 4 + rg;
        int col = bn0 + g.wn + j * 16 + g.m16;
        C[row * 1024 + col] = f2bf((g.acc[i][j][rg] + bj[j]) * sc);
      }
}

// Output projection: fp32 row-major out.
__global__ __launch_bounds__(256) void k_gemm_out(const short* __restrict__ A,
                                                  const short* __restrict__ Wo,
                                                  const float* __restrict__ bo,
                                                  float* __restrict__ C) {
  __shared__ short As[8192];
  __shared__ short Bs[8192];
  const int bn0 = blockIdx.x * 128, bm0 = blockIdx.y * 128;
  GemmCore g;
  g.run(A, Wo, bm0, bn0, As, Bs);
  float bj[4];
#pragma unroll
  for (int j = 0; j < 4; ++j) bj[j] = bo[bn0 + g.wn + j * 16 + g.m16];
#pragma unroll
  for (int i = 0; i < 4; ++i)
#pragma unroll
    for (int j = 0; j < 4; ++j)
#pragma unroll
      for (int rg = 0; rg < 4; ++rg) {
        int row = bm0 + g.wm + i * 16 + g.quad * 4 + rg;
        int col = bn0 + g.wn + j * 16 + g.m16;
        C[row * 1024 + col] = g.acc[i][j][rg] + bj[j];
      }
}

// Flash-style attention, S^T formulation (R5 version, unchanged).
__global__ __launch_bounds__(256, 3) void k_attn(const short* __restrict__ Q,
                                                 const short* __restrict__ Km,
                                                 const short* __restrict__ Vt,
                                                 const float* __restrict__ Mg,
                                                 short* __restrict__ Out) {
  __shared__ __attribute__((aligned(16))) short U[8448];   // Qs then Ps (alias)
  __shared__ __attribute__((aligned(16))) short Ks[4096];  // 64x64, planes
  __shared__ __attribute__((aligned(16))) short Vs[4096];  // Vt: rows=d, cols=keys
  __shared__ __attribute__((aligned(16))) float Mk[64];

  const int tid = threadIdx.x;
  const int w = tid >> 6, lane = tid & 63;
  const int quad = lane >> 4, m16 = lane & 15;
  const int qb = blockIdx.x, hb = blockIdx.y;
  const int b = hb >> 4, h = hb & 15;
  const int wb = w * 2112;

  const short* Qh = Q + hb * (kL * kHD) + qb * 128 * kHD;
  const short* Kh = Km + hb * (kL * kHD);
  const short* Vh = Vt + hb * (kL * kHD);
  const float* Mb = Mg + b * kL;

#pragma unroll
  for (int p = 0; p < 4; ++p) {
    int ci = p * 256 + tid;
    int r = ci & 127, kc = ci >> 7;
    load_lds16(Qh + r * 64 + kc * 8, &U[ci * 8]);
  }
  __syncthreads();
  bf16x8 qf[2][2];
#pragma unroll
  for (int i = 0; i < 2; ++i)
#pragma unroll
    for (int s = 0; s < 2; ++s)
      qf[i][s] = *reinterpret_cast<const bf16x8*>(
          &U[(s * 4 + quad) * 1024 + (w * 32 + i * 16 + m16) * 8]);

  bf16x8 ones;
#pragma unroll
  for (int e = 0; e < 8; ++e) ones[e] = (short)0x3F80;  // bf16 1.0

  f32x4 oacc[2][4] = {};
  f32x4 lacc[2] = {};

  const int r6 = tid & 63, kc6 = tid >> 6;
  for (int kb = 0; kb < 32; ++kb) {
    int kbase = kb * 64;
    load_lds16(Kh + (kbase + r6) * 64 + kc6 * 8, &Ks[tid * 8]);
    load_lds16(Kh + (kbase + r6) * 64 + (kc6 + 4) * 8, &Ks[(256 + tid) * 8]);
    load_lds16(Vh + r6 * 2048 + kbase + kc6 * 8, &Vs[tid * 8]);
    load_lds16(Vh + r6 * 2048 + kbase + (kc6 + 4) * 8, &Vs[(256 + tid) * 8]);
    load_lds4(Mb + kbase + lane, &Mk[lane]);
    __syncthreads();  // also orders all waves' qf reads before iter-0 Ps writes

    // S^T tiles: ST[j][i], j = key-tile (rows), i = q-tile (cols).
    f32x4 ST[4][2];
#pragma unroll
    for (int j = 0; j < 4; ++j) {
      float4 mj4 = *reinterpret_cast<const float4*>(&Mk[j * 16 + quad * 4]);
      f32x4 init; init[0] = mj4.x; init[1] = mj4.y; init[2] = mj4.z; init[3] = mj4.w;
#pragma unroll
      for (int i = 0; i < 2; ++i) ST[j][i] = init;
      bf16x8 kf0 = *reinterpret_cast<const bf16x8*>(
          &Ks[(0 * 4 + quad) * 512 + (j * 16 + m16) * 8]);
      bf16x8 kf1 = *reinterpret_cast<const bf16x8*>(
          &Ks[(1 * 4 + quad) * 512 + (j * 16 + m16) * 8]);
#pragma unroll
      for (int i = 0; i < 2; ++i) {
        ST[j][i] = __builtin_amdgcn_mfma_f32_16x16x32_bf16(kf0, qf[i][0], ST[j][i], 0, 0, 0);
        ST[j][i] = __builtin_amdgcn_mfma_f32_16x16x32_bf16(kf1, qf[i][1], ST[j][i], 0, 0, 0);
      }
    }

    // Softmax numerator + truncation pack + b64 spill into P (A-layout).
    const int kc_w = (quad >> 1);
    const int inner = (quad & 1) * 4;
#pragma unroll
    for (int j = 0; j < 4; ++j)
#pragma unroll
      for (int i = 0; i < 2; ++i) {
        float p0 = __builtin_amdgcn_exp2f(ST[j][i][0]);
        float p1 = __builtin_amdgcn_exp2f(ST[j][i][1]);
        float p2 = __builtin_amdgcn_exp2f(ST[j][i][2]);
        float p3 = __builtin_amdgcn_exp2f(ST[j][i][3]);
        uint2 pk;
        pk.x = __builtin_amdgcn_perm(__builtin_bit_cast(unsigned, p1),
                                     __builtin_bit_cast(unsigned, p0), 0x07060302u);
        pk.y = __builtin_amdgcn_perm(__builtin_bit_cast(unsigned, p3),
                                     __builtin_bit_cast(unsigned, p2), 0x07060302u);
        *reinterpret_cast<uint2*>(
            &U[wb + (j * 2 + kc_w) * 264 + (i * 16 + m16) * 8 + inner]) = pk;
      }
    asm volatile("s_waitcnt lgkmcnt(0)" ::: "memory");  // own-wave P RAW

    bf16x8 pf[2][2];
#pragma unroll
    for (int i = 0; i < 2; ++i)
#pragma unroll
      for (int s = 0; s < 2; ++s)
        pf[i][s] = *reinterpret_cast<const bf16x8*>(
            &U[wb + (s * 4 + quad) * 264 + (i * 16 + m16) * 8]);

    // l-accumulate via ones-MFMA: lacc rows == oacc rows (C-layout).
#pragma unroll
    for (int i = 0; i < 2; ++i) {
      lacc[i] = __builtin_amdgcn_mfma_f32_16x16x32_bf16(pf[i][0], ones, lacc[i], 0, 0, 0);
      lacc[i] = __builtin_amdgcn_mfma_f32_16x16x32_bf16(pf[i][1], ones, lacc[i], 0, 0, 0);
    }

#pragma unroll
    for (int j = 0; j < 4; ++j) {
      bf16x8 vf0 = *reinterpret_cast<const bf16x8*>(
          &Vs[(0 * 4 + quad) * 512 + (j * 16 + m16) * 8]);
      bf16x8 vf1 = *reinterpret_cast<const bf16x8*>(
          &Vs[(1 * 4 + quad) * 512 + (j * 16 + m16) * 8]);
#pragma unroll
      for (int i = 0; i < 2; ++i) {
        oacc[i][j] = __builtin_amdgcn_mfma_f32_16x16x32_bf16(pf[i][0], vf0, oacc[i][j], 0, 0, 0);
        oacc[i][j] = __builtin_amdgcn_mfma_f32_16x16x32_bf16(pf[i][1], vf1, oacc[i][j], 0, 0, 0);
      }
    }
    __syncthreads();
  }

#pragma unroll
  for (int i = 0; i < 2; ++i)
#pragma unroll
    for (int j = 0; j < 4; ++j) {
      int d = j * 16 + m16;
#pragma unroll
      for (int rg = 0; rg < 4; ++rg) {
        int ql = qb * 128 + w * 32 + i * 16 + quad * 4 + rg;
        Out[(b * kL + ql) * kE + h * kHD + d] =
            f2bf(oacc[i][j][rg] / lacc[i][rg]);
      }
    }
}

extern "C" void kernel_launch(void* const* d_in, const int* in_sizes, int n_in,
                              void* d_out, int out_size, void* d_ws, size_t ws_size,
                              hipStream_t stream) {
  const float* x  = (const float*)d_in[0];
  const int* mask = (const int*)d_in[1];
  const float* Wq = (const float*)d_in[2];
  const float* bq = (const float*)d_in[3];
  const float* Wk = (const float*)d_in[4];
  const float* bk = (const float*)d_in[5];
  const float* Wv = (const float*)d_in[6];
  const float* bv = (const float*)d_in[7];
  const float* Wo = (const float*)d_in[8];
  const float* bo = (const float*)d_in[9];

  short* ws  = (short*)d_ws;
  short* xb  = ws;                  // 8388608 shorts
  short* Wqb = xb  + 8388608;       // 4 x 1048576, contiguous
  short* Wkb = Wqb + 1048576;
  short* Wvb = Wkb + 1048576;
  short* Wob = Wvb + 1048576;
  short* Qb  = Wob + 1048576;       // 8388608 each
  short* Kb  = Qb  + 8388608;
  short* Vtb = Kb  + 8388608;
  short* AOb = Vtb + 8388608;       // doubles as Vl before attention runs
  float* Mkf = (float*)(AOb + 8388608);  // 8192 floats

  k_cvt<<<8192, 256, 0, stream>>>(x, xb, 8388608);
  k_cvtw<<<4128, 256, 0, stream>>>(Wq, Wk, Wv, Wo, mask, Wqb, Mkf);

  // V row-major into AOb (dead until attention), then transpose into Vtb.
  k_gemm_qkv<<<dim3(24, 64), 256, 0, stream>>>(xb, Wqb, Wkb, Wvb, bq, bk, bv, Qb, Kb, AOb);
  k_trv<<<dim3(32, 64), 256, 0, stream>>>(AOb, Vtb);
  k_attn<<<dim3(16, 64), 256, 0, stream>>>(Qb, Kb, Vtb, Mkf, AOb);
  k_gemm_out<<<dim3(8, 64), 256, 0, stream>>>(AOb, Wob, bo, (float*)d_out);
}

// Round 10
// 333.993 us; speedup vs baseline: 1.0725x; 1.0725x over previous
//
#include <hip/hip_runtime.h>
#include <hip/hip_bf16.h>

// Problem: B=4, L=2048, E=1024, H=16, HD=64.
// NOTE: the reference's _separate_heads is reshape(B,L,E)->(B,H,L,HD) with NO
// transpose: head h = (l>>7)&15 comes from the SEQUENCE dim; per-head seq
// index l' = (l&127)*16 + (e>>6) mixes row and col. The flat (B,L,E) buffer
// IS the (B,H,L,HD) buffer, so row-major Q/K/V can be read per-head directly;
// only the attention V-operand needs a (l',d)->(d,l') transpose (k_trv).
// A fused V-transpose epilogue is non-coalescable under this mapping (R7/R8).
namespace {
constexpr int kB = 4, kL = 2048, kE = 1024, kH = 16, kHD = 64;
constexpr float kCs = 0.18033688f;  // log2(e)/8, folded into Q projection
}

typedef __attribute__((ext_vector_type(8))) short bf16x8;
typedef __attribute__((ext_vector_type(4))) float f32x4;

__device__ __forceinline__ short f2bf(float f) {
  __hip_bfloat16 h = __float2bfloat16(f);
  return *reinterpret_cast<short*>(&h);
}

__device__ __forceinline__ void load_lds16(const void* g, void* l) {
  __builtin_amdgcn_global_load_lds((const __attribute__((address_space(1))) void*)g,
                                   (__attribute__((address_space(3))) void*)l, 16, 0, 0);
}
__device__ __forceinline__ void load_lds4(const void* g, void* l) {
  __builtin_amdgcn_global_load_lds((const __attribute__((address_space(1))) void*)g,
                                   (__attribute__((address_space(3))) void*)l, 4, 0, 0);
}

// fp32 -> bf16 cast, 4 elems/thread
__global__ __launch_bounds__(256) void k_cvt(const float* __restrict__ s,
                                             short* __restrict__ d, int n) {
  int i = (blockIdx.x * 256 + threadIdx.x) * 4;
  if (i < n) {
    float4 v = *reinterpret_cast<const float4*>(s + i);
    short4 o;
    o.x = f2bf(v.x); o.y = f2bf(v.y); o.z = f2bf(v.z); o.w = f2bf(v.w);
    *reinterpret_cast<short4*>(d + i) = o;
  }
}

// 4 weight casts + mask->float-offset precompute, one dispatch.
__global__ __launch_bounds__(256) void k_cvtw(const float* __restrict__ w0,
                                              const float* __restrict__ w1,
                                              const float* __restrict__ w2,
                                              const float* __restrict__ w3,
                                              const int* __restrict__ mask,
                                              short* __restrict__ dst,
                                              float* __restrict__ mkf) {
  int bx = blockIdx.x;
  if (bx >= 4096) {  // mask segment: 8192 elems
    int i = (bx - 4096) * 256 + threadIdx.x;
    mkf[i] = mask[i] != 0 ? -10.0f : -1.0e10f;
    return;
  }
  int seg = bx >> 10;
  const float* s = seg == 0 ? w0 : seg == 1 ? w1 : seg == 2 ? w2 : w3;
  int local = ((bx & 1023) * 256 + threadIdx.x) * 4;
  float4 v = *reinterpret_cast<const float4*>(s + local);
  short4 o;
  o.x = f2bf(v.x); o.y = f2bf(v.y); o.z = f2bf(v.z); o.w = f2bf(v.w);
  *reinterpret_cast<short4*>(dst + seg * 1048576 + local) = o;
}

// Per-head V transpose: Vl[hb][l'][d] -> Vt[hb][d][l']. 64x64 tiles via LDS,
// both global sides coalesced. (hb/l' are the flat-reinterpretation indices —
// this kernel is agnostic to their meaning.)
__global__ __launch_bounds__(256) void k_trv(const short* __restrict__ Vl,
                                             short* __restrict__ Vt) {
  __shared__ unsigned T[64 * 33];
  const int t = threadIdx.x;
  const int hb = blockIdx.y;
  const int l0 = blockIdx.x * 64;
  const short* src = Vl + hb * 131072;
  short* dst = Vt + hb * 131072;
  const int d8 = (t & 7) * 8;
  const int lp = t >> 3;
  const uint4 va = *reinterpret_cast<const uint4*>(src + (l0 + 2 * lp) * 64 + d8);
  const uint4 vb = *reinterpret_cast<const uint4*>(src + (l0 + 2 * lp + 1) * 64 + d8);
  const unsigned a[4] = {va.x, va.y, va.z, va.w};
  const unsigned b[4] = {vb.x, vb.y, vb.z, vb.w};
#pragma unroll
  for (int j = 0; j < 4; ++j) {
    unsigned z0 = __builtin_amdgcn_perm(b[j], a[j], 0x05040100u);
    unsigned z1 = __builtin_amdgcn_perm(b[j], a[j], 0x07060302u);
    T[(d8 + 2 * j) * 33 + lp] = z0;
    T[(d8 + 2 * j + 1) * 33 + lp] = z1;
  }
  __syncthreads();
  const int u = (t & 7) * 4;
#pragma unroll
  for (int h2 = 0; h2 < 2; ++h2) {
    int d = (t >> 3) + h2 * 32;
    uint4 r;
    r.x = T[d * 33 + u];     r.y = T[d * 33 + u + 1];
    r.z = T[d * 33 + u + 2]; r.w = T[d * 33 + u + 3];
    *reinterpret_cast<uint4*>(dst + d * 2048 + l0 + u * 2) = r;
  }
}

// ---- shared GEMM core: 128x128 tile, BK=32, NT, k-major chunk-plane LDS ----
struct GemmCore {
  f32x4 acc[4][4];
  int tid, w, lane, quad, m16, wm, wn, r0, kc0;
  __device__ __forceinline__ void run(const short* __restrict__ A,
                                      const short* __restrict__ W,
                                      int bm0, int bn0, short* As, short* Bs) {
    const int K = 1024;
    tid = threadIdx.x;
    w = tid >> 6; lane = tid & 63; quad = lane >> 4; m16 = lane & 15;
    wm = (w >> 1) * 64; wn = (w & 1) * 64;
    r0 = tid & 127; kc0 = tid >> 7;
#pragma unroll
    for (int i = 0; i < 4; ++i)
#pragma unroll
      for (int j = 0; j < 4; ++j) acc[i][j] = (f32x4){0, 0, 0, 0};
    const short* Arow = A + (bm0 + r0) * K + kc0 * 8;
    const short* Wrow = W + (bn0 + r0) * K + kc0 * 8;
    short* As0 = &As[tid * 8]; short* As1 = &As[(256 + tid) * 8];
    short* Bs0 = &Bs[tid * 8]; short* Bs1 = &Bs[(256 + tid) * 8];
    for (int kt = 0; kt < K; kt += 32) {
      load_lds16(Arow + kt, As0);
      load_lds16(Arow + kt + 16, As1);
      load_lds16(Wrow + kt, Bs0);
      load_lds16(Wrow + kt + 16, Bs1);
      __syncthreads();
      bf16x8 a[4], b[4];
#pragma unroll
      for (int i = 0; i < 4; ++i)
        a[i] = *reinterpret_cast<const bf16x8*>(&As[quad * 1024 + (wm + i * 16 + m16) * 8]);
#pragma unroll
      for (int j = 0; j < 4; ++j)
        b[j] = *reinterpret_cast<const bf16x8*>(&Bs[quad * 1024 + (wn + j * 16 + m16) * 8]);
#pragma unroll
      for (int i = 0; i < 4; ++i)
#pragma unroll
        for (int j = 0; j < 4; ++j)
          acc[i][j] = __builtin_amdgcn_mfma_f32_16x16x32_bf16(a[i], b[j], acc[i][j], 0, 0, 0);
      __syncthreads();
    }
  }
};

// Fused Q/K/V projection, XCD-swizzled: linear block id l -> (bm, colsel)
// such that all 24 col-blocks sharing one A-tile land on the same XCD
// (id%8), making the per-XCD A working set 8 tiles x 256 KB = 2 MB (fits L2).
__global__ __launch_bounds__(256) void k_gemm_qkv(const short* __restrict__ xb,
                                                  const short* __restrict__ Wq,
                                                  const short* __restrict__ Wk,
                                                  const short* __restrict__ Wv,
                                                  const float* __restrict__ bq,
                                                  const float* __restrict__ bk,
                                                  const float* __restrict__ bv,
                                                  short* __restrict__ Q,
                                                  short* __restrict__ K,
                                                  short* __restrict__ Vl) {
  __shared__ short As[4096];
  __shared__ short Bs[4096];
  const int l = blockIdx.x + 24 * blockIdx.y;  // 0..1535
  const int xcd = l & 7, wv_ = l >> 3;         // wv_: 0..191
  const int bm0 = (xcd + 8 * (wv_ & 7)) * 128;
  const int colsel = wv_ >> 3;                 // 0..23
  const int sel = colsel >> 3;
  const int bn0 = (colsel & 7) * 128;
  const short* W = sel == 0 ? Wq : sel == 1 ? Wk : Wv;
  const float* bias = sel == 0 ? bq : sel == 1 ? bk : bv;

  GemmCore g;
  g.run(xb, W, bm0, bn0, As, Bs);

  float bj[4];
#pragma unroll
  for (int j = 0; j < 4; ++j) bj[j] = bias[bn0 + g.wn + j * 16 + g.m16];

  short* C = sel == 0 ? Q : sel == 1 ? K : Vl;
  float sc = sel == 0 ? kCs : 1.0f;
#pragma unroll
  for (int i = 0; i < 4; ++i)
#pragma unroll
    for (int j = 0; j < 4; ++j)
#pragma unroll
      for (int rg = 0; rg < 4; ++rg) {
        int row = bm0 + g.wm + i * 16 + g.quad * 4 + rg;
        int col = bn0 + g.wn + j * 16 + g.m16;
        C[row * 1024 + col] = f2bf((g.acc[i][j][rg] + bj[j]) * sc);
      }
}

// Output projection: fp32 row-major out. Same XCD swizzle (8 cols share A).
__global__ __launch_bounds__(256) void k_gemm_out(const short* __restrict__ A,
                                                  const short* __restrict__ Wo,
                                                  const float* __restrict__ bo,
                                                  float* __restrict__ C) {
  __shared__ short As[4096];
  __shared__ short Bs[4096];
  const int l = blockIdx.x + 8 * blockIdx.y;  // 0..511
  const int xcd = l & 7, wv_ = l >> 3;        // wv_: 0..63
  const int bm0 = (xcd + 8 * (wv_ & 7)) * 128;
  const int bn0 = (wv_ >> 3) * 128;
  GemmCore g;
  g.run(A, Wo, bm0, bn0, As, Bs);
  float bj[4];
#pragma unroll
  for (int j = 0; j < 4; ++j) bj[j] = bo[bn0 + g.wn + j * 16 + g.m16];
#pragma unroll
  for (int i = 0; i < 4; ++i)
#pragma unroll
    for (int j = 0; j < 4; ++j)
#pragma unroll
      for (int rg = 0; rg < 4; ++rg) {
        int row = bm0 + g.wm + i * 16 + g.quad * 4 + rg;
        int col = bn0 + g.wn + j * 16 + g.m16;
        C[row * 1024 + col] = g.acc[i][j][rg] + bj[j];
      }
}

// Flash-style attention, S^T formulation (R5 version). XCD swizzle: the 16
// q-blocks of one head (sharing 0.5 MB K+V) pin to one XCD; 8 heads/XCD = 4MB.
__global__ __launch_bounds__(256, 3) void k_attn(const short* __restrict__ Q,
                                                 const short* __restrict__ Km,
                                                 const short* __restrict__ Vt,
                                                 const float* __restrict__ Mg,
                                                 short* __restrict__ Out) {
  __shared__ __attribute__((aligned(16))) short U[8448];   // Qs then Ps (alias)
  __shared__ __attribute__((aligned(16))) short Ks[4096];  // 64x64, planes
  __shared__ __attribute__((aligned(16))) short Vs[4096];  // Vt: rows=d, cols=keys
  __shared__ __attribute__((aligned(16))) float Mk[64];

  const int tid = threadIdx.x;
  const int w = tid >> 6, lane = tid & 63;
  const int quad = lane >> 4, m16 = lane & 15;
  const int lid = blockIdx.x + 16 * blockIdx.y;  // 0..1023
  const int xcd = lid & 7, wv_ = lid >> 3;       // wv_: 0..127
  const int hb = xcd + 8 * (wv_ & 7);
  const int qb = wv_ >> 3;                       // 0..15
  const int b = hb >> 4, h = hb & 15;
  const int wb = w * 2112;

  const short* Qh = Q + hb * (kL * kHD) + qb * 128 * kHD;
  const short* Kh = Km + hb * (kL * kHD);
  const short* Vh = Vt + hb * (kL * kHD);
  const float* Mb = Mg + b * kL;

#pragma unroll
  for (int p = 0; p < 4; ++p) {
    int ci = p * 256 + tid;
    int r = ci & 127, kc = ci >> 7;
    load_lds16(Qh + r * 64 + kc * 8, &U[ci * 8]);
  }
  __syncthreads();
  bf16x8 qf[2][2];
#pragma unroll
  for (int i = 0; i < 2; ++i)
#pragma unroll
    for (int s = 0; s < 2; ++s)
      qf[i][s] = *reinterpret_cast<const bf16x8*>(
          &U[(s * 4 + quad) * 1024 + (w * 32 + i * 16 + m16) * 8]);

  bf16x8 ones;
#pragma unroll
  for (int e = 0; e < 8; ++e) ones[e] = (short)0x3F80;  // bf16 1.0

  f32x4 oacc[2][4] = {};
  f32x4 lacc[2] = {};

  const int r6 = tid & 63, kc6 = tid >> 6;
  for (int kb = 0; kb < 32; ++kb) {
    int kbase = kb * 64;
    load_lds16(Kh + (kbase + r6) * 64 + kc6 * 8, &Ks[tid * 8]);
    load_lds16(Kh + (kbase + r6) * 64 + (kc6 + 4) * 8, &Ks[(256 + tid) * 8]);
    load_lds16(Vh + r6 * 2048 + kbase + kc6 * 8, &Vs[tid * 8]);
    load_lds16(Vh + r6 * 2048 + kbase + (kc6 + 4) * 8, &Vs[(256 + tid) * 8]);
    load_lds4(Mb + kbase + lane, &Mk[lane]);
    __syncthreads();  // also orders all waves' qf reads before iter-0 Ps writes

    // S^T tiles: ST[j][i], j = key-tile (rows), i = q-tile (cols).
    f32x4 ST[4][2];
#pragma unroll
    for (int j = 0; j < 4; ++j) {
      float4 mj4 = *reinterpret_cast<const float4*>(&Mk[j * 16 + quad * 4]);
      f32x4 init; init[0] = mj4.x; init[1] = mj4.y; init[2] = mj4.z; init[3] = mj4.w;
#pragma unroll
      for (int i = 0; i < 2; ++i) ST[j][i] = init;
      bf16x8 kf0 = *reinterpret_cast<const bf16x8*>(
          &Ks[(0 * 4 + quad) * 512 + (j * 16 + m16) * 8]);
      bf16x8 kf1 = *reinterpret_cast<const bf16x8*>(
          &Ks[(1 * 4 + quad) * 512 + (j * 16 + m16) * 8]);
#pragma unroll
      for (int i = 0; i < 2; ++i) {
        ST[j][i] = __builtin_amdgcn_mfma_f32_16x16x32_bf16(kf0, qf[i][0], ST[j][i], 0, 0, 0);
        ST[j][i] = __builtin_amdgcn_mfma_f32_16x16x32_bf16(kf1, qf[i][1], ST[j][i], 0, 0, 0);
      }
    }

    // Softmax numerator + truncation pack + b64 spill into P (A-layout).
    const int kc_w = (quad >> 1);
    const int inner = (quad & 1) * 4;
#pragma unroll
    for (int j = 0; j < 4; ++j)
#pragma unroll
      for (int i = 0; i < 2; ++i) {
        float p0 = __builtin_amdgcn_exp2f(ST[j][i][0]);
        float p1 = __builtin_amdgcn_exp2f(ST[j][i][1]);
        float p2 = __builtin_amdgcn_exp2f(ST[j][i][2]);
        float p3 = __builtin_amdgcn_exp2f(ST[j][i][3]);
        uint2 pk;
        pk.x = __builtin_amdgcn_perm(__builtin_bit_cast(unsigned, p1),
                                     __builtin_bit_cast(unsigned, p0), 0x07060302u);
        pk.y = __builtin_amdgcn_perm(__builtin_bit_cast(unsigned, p3),
                                     __builtin_bit_cast(unsigned, p2), 0x07060302u);
        *reinterpret_cast<uint2*>(
            &U[wb + (j * 2 + kc_w) * 264 + (i * 16 + m16) * 8 + inner]) = pk;
      }
    asm volatile("s_waitcnt lgkmcnt(0)" ::: "memory");  // own-wave P RAW

    bf16x8 pf[2][2];
#pragma unroll
    for (int i = 0; i < 2; ++i)
#pragma unroll
      for (int s = 0; s < 2; ++s)
        pf[i][s] = *reinterpret_cast<const bf16x8*>(
            &U[wb + (s * 4 + quad) * 264 + (i * 16 + m16) * 8]);

    // l-accumulate via ones-MFMA: lacc rows == oacc rows (C-layout).
#pragma unroll
    for (int i = 0; i < 2; ++i) {
      lacc[i] = __builtin_amdgcn_mfma_f32_16x16x32_bf16(pf[i][0], ones, lacc[i], 0, 0, 0);
      lacc[i] = __builtin_amdgcn_mfma_f32_16x16x32_bf16(pf[i][1], ones, lacc[i], 0, 0, 0);
    }

#pragma unroll
    for (int j = 0; j < 4; ++j) {
      bf16x8 vf0 = *reinterpret_cast<const bf16x8*>(
          &Vs[(0 * 4 + quad) * 512 + (j * 16 + m16) * 8]);
      bf16x8 vf1 = *reinterpret_cast<const bf16x8*>(
          &Vs[(1 * 4 + quad) * 512 + (j * 16 + m16) * 8]);
#pragma unroll
      for (int i = 0; i < 2; ++i) {
        oacc[i][j] = __builtin_amdgcn_mfma_f32_16x16x32_bf16(pf[i][0], vf0, oacc[i][j], 0, 0, 0);
        oacc[i][j] = __builtin_amdgcn_mfma_f32_16x16x32_bf16(pf[i][1], vf1, oacc[i][j], 0, 0, 0);
      }
    }
    __syncthreads();
  }

#pragma unroll
  for (int i = 0; i < 2; ++i)
#pragma unroll
    for (int j = 0; j < 4; ++j) {
      int d = j * 16 + m16;
#pragma unroll
      for (int rg = 0; rg < 4; ++rg) {
        int ql = qb * 128 + w * 32 + i * 16 + quad * 4 + rg;
        Out[(b * kL + ql) * kE + h * kHD + d] =
            f2bf(oacc[i][j][rg] / lacc[i][rg]);
      }
    }
}

extern "C" void kernel_launch(void* const* d_in, const int* in_sizes, int n_in,
                              void* d_out, int out_size, void* d_ws, size_t ws_size,
                              hipStream_t stream) {
  const float* x  = (const float*)d_in[0];
  const int* mask = (const int*)d_in[1];
  const float* Wq = (const float*)d_in[2];
  const float* bq = (const float*)d_in[3];
  const float* Wk = (const float*)d_in[4];
  const float* bk = (const float*)d_in[5];
  const float* Wv = (const float*)d_in[6];
  const float* bv = (const float*)d_in[7];
  const float* Wo = (const float*)d_in[8];
  const float* bo = (const float*)d_in[9];

  short* ws  = (short*)d_ws;
  short* xb  = ws;                  // 8388608 shorts
  short* Wqb = xb  + 8388608;       // 4 x 1048576, contiguous
  short* Wkb = Wqb + 1048576;
  short* Wvb = Wkb + 1048576;
  short* Wob = Wvb + 1048576;
  short* Qb  = Wob + 1048576;       // 8388608 each
  short* Kb  = Qb  + 8388608;
  short* Vtb = Kb  + 8388608;
  short* AOb = Vtb + 8388608;       // doubles as Vl before attention runs
  float* Mkf = (float*)(AOb + 8388608);  // 8192 floats

  k_cvt<<<8192, 256, 0, stream>>>(x, xb, 8388608);
  k_cvtw<<<4128, 256, 0, stream>>>(Wq, Wk, Wv, Wo, mask, Wqb, Mkf);

  // V row-major into AOb (dead until attention), then transpose into Vtb.
  k_gemm_qkv<<<dim3(24, 64), 256, 0, stream>>>(xb, Wqb, Wkb, Wvb, bq, bk, bv, Qb, Kb, AOb);
  k_trv<<<dim3(32, 64), 256, 0, stream>>>(AOb, Vtb);
  k_attn<<<dim3(16, 64), 256, 0, stream>>>(Qb, Kb, Vtb, Mkf, AOb);
  k_gemm_out<<<dim3(8, 64), 256, 0, stream>>>(AOb, Wob, bo, (float*)d_out);
}

// Round 11
// 333.112 us; speedup vs baseline: 1.0753x; 1.0026x over previous
//
#include <hip/hip_runtime.h>
#include <hip/hip_bf16.h>

// Problem: B=4, L=2048, E=1024, H=16, HD=64.
// NOTE: the reference's _separate_heads is reshape(B,L,E)->(B,H,L,HD) with NO
// transpose: the flat (B,L,E) buffer IS the (B,H,L,HD) buffer. Only the
// attention V-operand needs a (l',d)->(d,l') transpose (k_trv); a fused
// V-transpose epilogue is non-coalescable under this mapping (R7/R8).
namespace {
constexpr int kB = 4, kL = 2048, kE = 1024, kH = 16, kHD = 64;
constexpr float kCs = 0.18033688f;  // log2(e)/8, folded into Q projection
}

typedef __attribute__((ext_vector_type(8))) short bf16x8;
typedef __attribute__((ext_vector_type(4))) float f32x4;

__device__ __forceinline__ short f2bf(float f) {
  __hip_bfloat16 h = __float2bfloat16(f);
  return *reinterpret_cast<short*>(&h);
}

__device__ __forceinline__ void load_lds16(const void* g, void* l) {
  __builtin_amdgcn_global_load_lds((const __attribute__((address_space(1))) void*)g,
                                   (__attribute__((address_space(3))) void*)l, 16, 0, 0);
}
__device__ __forceinline__ void load_lds4(const void* g, void* l) {
  __builtin_amdgcn_global_load_lds((const __attribute__((address_space(1))) void*)g,
                                   (__attribute__((address_space(3))) void*)l, 4, 0, 0);
}

// fp32 -> bf16 cast, 4 elems/thread
__global__ __launch_bounds__(256) void k_cvt(const float* __restrict__ s,
                                             short* __restrict__ d, int n) {
  int i = (blockIdx.x * 256 + threadIdx.x) * 4;
  if (i < n) {
    float4 v = *reinterpret_cast<const float4*>(s + i);
    short4 o;
    o.x = f2bf(v.x); o.y = f2bf(v.y); o.z = f2bf(v.z); o.w = f2bf(v.w);
    *reinterpret_cast<short4*>(d + i) = o;
  }
}

// 4 weight casts + mask->float-offset precompute, one dispatch.
__global__ __launch_bounds__(256) void k_cvtw(const float* __restrict__ w0,
                                              const float* __restrict__ w1,
                                              const float* __restrict__ w2,
                                              const float* __restrict__ w3,
                                              const int* __restrict__ mask,
                                              short* __restrict__ dst,
                                              float* __restrict__ mkf) {
  int bx = blockIdx.x;
  if (bx >= 4096) {  // mask segment: 8192 elems
    int i = (bx - 4096) * 256 + threadIdx.x;
    mkf[i] = mask[i] != 0 ? -10.0f : -1.0e10f;
    return;
  }
  int seg = bx >> 10;
  const float* s = seg == 0 ? w0 : seg == 1 ? w1 : seg == 2 ? w2 : w3;
  int local = ((bx & 1023) * 256 + threadIdx.x) * 4;
  float4 v = *reinterpret_cast<const float4*>(s + local);
  short4 o;
  o.x = f2bf(v.x); o.y = f2bf(v.y); o.z = f2bf(v.z); o.w = f2bf(v.w);
  *reinterpret_cast<short4*>(dst + seg * 1048576 + local) = o;
}

// Per-head V transpose: Vl[hb][l'][d] -> Vt[hb][d][l']. 64x64 tiles via LDS,
// both global sides coalesced.
__global__ __launch_bounds__(256) void k_trv(const short* __restrict__ Vl,
                                             short* __restrict__ Vt) {
  __shared__ unsigned T[64 * 33];
  const int t = threadIdx.x;
  const int hb = blockIdx.y;
  const int l0 = blockIdx.x * 64;
  const short* src = Vl + hb * 131072;
  short* dst = Vt + hb * 131072;
  const int d8 = (t & 7) * 8;
  const int lp = t >> 3;
  const uint4 va = *reinterpret_cast<const uint4*>(src + (l0 + 2 * lp) * 64 + d8);
  const uint4 vb = *reinterpret_cast<const uint4*>(src + (l0 + 2 * lp + 1) * 64 + d8);
  const unsigned a[4] = {va.x, va.y, va.z, va.w};
  const unsigned b[4] = {vb.x, vb.y, vb.z, vb.w};
#pragma unroll
  for (int j = 0; j < 4; ++j) {
    unsigned z0 = __builtin_amdgcn_perm(b[j], a[j], 0x05040100u);
    unsigned z1 = __builtin_amdgcn_perm(b[j], a[j], 0x07060302u);
    T[(d8 + 2 * j) * 33 + lp] = z0;
    T[(d8 + 2 * j + 1) * 33 + lp] = z1;
  }
  __syncthreads();
  const int u = (t & 7) * 4;
#pragma unroll
  for (int h2 = 0; h2 < 2; ++h2) {
    int d = (t >> 3) + h2 * 32;
    uint4 r;
    r.x = T[d * 33 + u];     r.y = T[d * 33 + u + 1];
    r.z = T[d * 33 + u + 2]; r.w = T[d * 33 + u + 3];
    *reinterpret_cast<uint4*>(dst + d * 2048 + l0 + u * 2) = r;
  }
}

// ---- shared GEMM core: 128x128 tile, BK=32, NT, k-major chunk-plane LDS ----
// R10: register diet — j-outer/i-inner MFMA loop with TRANSIENT b fragment
// (liveness 8 regs, not 32). Combined VGPR+AGPR targets <=128 so that
// __launch_bounds__(256,4) on the callers yields 4 waves/SIMD (R9 showed the
// 64-AGPR accumulator pushed combined regs to ~144 -> 3 waves/SIMD cap;
// CSV VGPR_Count excludes AGPRs).
struct GemmCore {
  f32x4 acc[4][4];
  int tid, w, lane, quad, m16, wm, wn, r0, kc0;
  __device__ __forceinline__ void run(const short* __restrict__ A,
                                      const short* __restrict__ W,
                                      int bm0, int bn0, short* As, short* Bs) {
    const int K = 1024;
    tid = threadIdx.x;
    w = tid >> 6; lane = tid & 63; quad = lane >> 4; m16 = lane & 15;
    wm = (w >> 1) * 64; wn = (w & 1) * 64;
    r0 = tid & 127; kc0 = tid >> 7;
#pragma unroll
    for (int i = 0; i < 4; ++i)
#pragma unroll
      for (int j = 0; j < 4; ++j) acc[i][j] = (f32x4){0, 0, 0, 0};
    const short* Arow = A + (bm0 + r0) * K + kc0 * 8;
    const short* Wrow = W + (bn0 + r0) * K + kc0 * 8;
    short* As0 = &As[tid * 8]; short* As1 = &As[(256 + tid) * 8];
    short* Bs0 = &Bs[tid * 8]; short* Bs1 = &Bs[(256 + tid) * 8];
    for (int kt = 0; kt < K; kt += 32) {
      load_lds16(Arow + kt, As0);
      load_lds16(Arow + kt + 16, As1);
      load_lds16(Wrow + kt, Bs0);
      load_lds16(Wrow + kt + 16, Bs1);
      __syncthreads();
      bf16x8 a[4];
#pragma unroll
      for (int i = 0; i < 4; ++i)
        a[i] = *reinterpret_cast<const bf16x8*>(&As[quad * 1024 + (wm + i * 16 + m16) * 8]);
#pragma unroll
      for (int j = 0; j < 4; ++j) {
        bf16x8 b = *reinterpret_cast<const bf16x8*>(&Bs[quad * 1024 + (wn + j * 16 + m16) * 8]);
#pragma unroll
        for (int i = 0; i < 4; ++i)
          acc[i][j] = __builtin_amdgcn_mfma_f32_16x16x32_bf16(a[i], b, acc[i][j], 0, 0, 0);
      }
      __syncthreads();
    }
  }
};

// Fused Q/K/V projection, XCD-swizzled (R9): all 24 col-blocks sharing one
// A-tile land on the same XCD -> per-XCD A working set 2 MB (L2-resident).
__global__ __launch_bounds__(256, 4) void k_gemm_qkv(const short* __restrict__ xb,
                                                     const short* __restrict__ Wq,
                                                     const short* __restrict__ Wk,
                                                     const short* __restrict__ Wv,
                                                     const float* __restrict__ bq,
                                                     const float* __restrict__ bk,
                                                     const float* __restrict__ bv,
                                                     short* __restrict__ Q,
                                                     short* __restrict__ K,
                                                     short* __restrict__ Vl) {
  __shared__ short As[4096];
  __shared__ short Bs[4096];
  const int l = blockIdx.x + 24 * blockIdx.y;  // 0..1535
  const int xcd = l & 7, wv_ = l >> 3;         // wv_: 0..191
  const int bm0 = (xcd + 8 * (wv_ & 7)) * 128;
  const int colsel = wv_ >> 3;                 // 0..23
  const int sel = colsel >> 3;
  const int bn0 = (colsel & 7) * 128;
  const short* W = sel == 0 ? Wq : sel == 1 ? Wk : Wv;
  const float* bias = sel == 0 ? bq : sel == 1 ? bk : bv;

  GemmCore g;
  g.run(xb, W, bm0, bn0, As, Bs);

  float bj[4];
#pragma unroll
  for (int j = 0; j < 4; ++j) bj[j] = bias[bn0 + g.wn + j * 16 + g.m16];

  short* C = sel == 0 ? Q : sel == 1 ? K : Vl;
  float sc = sel == 0 ? kCs : 1.0f;
#pragma unroll
  for (int i = 0; i < 4; ++i)
#pragma unroll
    for (int j = 0; j < 4; ++j)
#pragma unroll
      for (int rg = 0; rg < 4; ++rg) {
        int row = bm0 + g.wm + i * 16 + g.quad * 4 + rg;
        int col = bn0 + g.wn + j * 16 + g.m16;
        C[row * 1024 + col] = f2bf((g.acc[i][j][rg] + bj[j]) * sc);
      }
}

// Output projection: fp32 row-major out. Same XCD swizzle (8 cols share A).
__global__ __launch_bounds__(256, 4) void k_gemm_out(const short* __restrict__ A,
                                                     const short* __restrict__ Wo,
                                                     const float* __restrict__ bo,
                                                     float* __restrict__ C) {
  __shared__ short As[4096];
  __shared__ short Bs[4096];
  const int l = blockIdx.x + 8 * blockIdx.y;  // 0..511
  const int xcd = l & 7, wv_ = l >> 3;        // wv_: 0..63
  const int bm0 = (xcd + 8 * (wv_ & 7)) * 128;
  const int bn0 = (wv_ >> 3) * 128;
  GemmCore g;
  g.run(A, Wo, bm0, bn0, As, Bs);
  float bj[4];
#pragma unroll
  for (int j = 0; j < 4; ++j) bj[j] = bo[bn0 + g.wn + j * 16 + g.m16];
#pragma unroll
  for (int i = 0; i < 4; ++i)
#pragma unroll
    for (int j = 0; j < 4; ++j)
#pragma unroll
      for (int rg = 0; rg < 4; ++rg) {
        int row = bm0 + g.wm + i * 16 + g.quad * 4 + rg;
        int col = bn0 + g.wn + j * 16 + g.m16;
        C[row * 1024 + col] = g.acc[i][j][rg] + bj[j];
      }
}

// Flash-style attention, S^T formulation (R5 version + R9 XCD swizzle).
__global__ __launch_bounds__(256, 3) void k_attn(const short* __restrict__ Q,
                                                 const short* __restrict__ Km,
                                                 const short* __restrict__ Vt,
                                                 const float* __restrict__ Mg,
                                                 short* __restrict__ Out) {
  __shared__ __attribute__((aligned(16))) short U[8448];   // Qs then Ps (alias)
  __shared__ __attribute__((aligned(16))) short Ks[4096];  // 64x64, planes
  __shared__ __attribute__((aligned(16))) short Vs[4096];  // Vt: rows=d, cols=keys
  __shared__ __attribute__((aligned(16))) float Mk[64];

  const int tid = threadIdx.x;
  const int w = tid >> 6, lane = tid & 63;
  const int quad = lane >> 4, m16 = lane & 15;
  const int lid = blockIdx.x + 16 * blockIdx.y;  // 0..1023
  const int xcd = lid & 7, wv_ = lid >> 3;       // wv_: 0..127
  const int hb = xcd + 8 * (wv_ & 7);
  const int qb = wv_ >> 3;                       // 0..15
  const int b = hb >> 4, h = hb & 15;
  const int wb = w * 2112;

  const short* Qh = Q + hb * (kL * kHD) + qb * 128 * kHD;
  const short* Kh = Km + hb * (kL * kHD);
  const short* Vh = Vt + hb * (kL * kHD);
  const float* Mb = Mg + b * kL;

#pragma unroll
  for (int p = 0; p < 4; ++p) {
    int ci = p * 256 + tid;
    int r = ci & 127, kc = ci >> 7;
    load_lds16(Qh + r * 64 + kc * 8, &U[ci * 8]);
  }
  __syncthreads();
  bf16x8 qf[2][2];
#pragma unroll
  for (int i = 0; i < 2; ++i)
#pragma unroll
    for (int s = 0; s < 2; ++s)
      qf[i][s] = *reinterpret_cast<const bf16x8*>(
          &U[(s * 4 + quad) * 1024 + (w * 32 + i * 16 + m16) * 8]);

  bf16x8 ones;
#pragma unroll
  for (int e = 0; e < 8; ++e) ones[e] = (short)0x3F80;  // bf16 1.0

  f32x4 oacc[2][4] = {};
  f32x4 lacc[2] = {};

  const int r6 = tid & 63, kc6 = tid >> 6;
  for (int kb = 0; kb < 32; ++kb) {
    int kbase = kb * 64;
    load_lds16(Kh + (kbase + r6) * 64 + kc6 * 8, &Ks[tid * 8]);
    load_lds16(Kh + (kbase + r6) * 64 + (kc6 + 4) * 8, &Ks[(256 + tid) * 8]);
    load_lds16(Vh + r6 * 2048 + kbase + kc6 * 8, &Vs[tid * 8]);
    load_lds16(Vh + r6 * 2048 + kbase + (kc6 + 4) * 8, &Vs[(256 + tid) * 8]);
    load_lds4(Mb + kbase + lane, &Mk[lane]);
    __syncthreads();  // also orders all waves' qf reads before iter-0 Ps writes

    // S^T tiles: ST[j][i], j = key-tile (rows), i = q-tile (cols).
    f32x4 ST[4][2];
#pragma unroll
    for (int j = 0; j < 4; ++j) {
      float4 mj4 = *reinterpret_cast<const float4*>(&Mk[j * 16 + quad * 4]);
      f32x4 init; init[0] = mj4.x; init[1] = mj4.y; init[2] = mj4.z; init[3] = mj4.w;
#pragma unroll
      for (int i = 0; i < 2; ++i) ST[j][i] = init;
      bf16x8 kf0 = *reinterpret_cast<const bf16x8*>(
          &Ks[(0 * 4 + quad) * 512 + (j * 16 + m16) * 8]);
      bf16x8 kf1 = *reinterpret_cast<const bf16x8*>(
          &Ks[(1 * 4 + quad) * 512 + (j * 16 + m16) * 8]);
#pragma unroll
      for (int i = 0; i < 2; ++i) {
        ST[j][i] = __builtin_amdgcn_mfma_f32_16x16x32_bf16(kf0, qf[i][0], ST[j][i], 0, 0, 0);
        ST[j][i] = __builtin_amdgcn_mfma_f32_16x16x32_bf16(kf1, qf[i][1], ST[j][i], 0, 0, 0);
      }
    }

    // Softmax numerator + truncation pack + b64 spill into P (A-layout).
    const int kc_w = (quad >> 1);
    const int inner = (quad & 1) * 4;
#pragma unroll
    for (int j = 0; j < 4; ++j)
#pragma unroll
      for (int i = 0; i < 2; ++i) {
        float p0 = __builtin_amdgcn_exp2f(ST[j][i][0]);
        float p1 = __builtin_amdgcn_exp2f(ST[j][i][1]);
        float p2 = __builtin_amdgcn_exp2f(ST[j][i][2]);
        float p3 = __builtin_amdgcn_exp2f(ST[j][i][3]);
        uint2 pk;
        pk.x = __builtin_amdgcn_perm(__builtin_bit_cast(unsigned, p1),
                                     __builtin_bit_cast(unsigned, p0), 0x07060302u);
        pk.y = __builtin_amdgcn_perm(__builtin_bit_cast(unsigned, p3),
                                     __builtin_bit_cast(unsigned, p2), 0x07060302u);
        *reinterpret_cast<uint2*>(
            &U[wb + (j * 2 + kc_w) * 264 + (i * 16 + m16) * 8 + inner]) = pk;
      }
    asm volatile("s_waitcnt lgkmcnt(0)" ::: "memory");  // own-wave P RAW

    bf16x8 pf[2][2];
#pragma unroll
    for (int i = 0; i < 2; ++i)
#pragma unroll
      for (int s = 0; s < 2; ++s)
        pf[i][s] = *reinterpret_cast<const bf16x8*>(
            &U[wb + (s * 4 + quad) * 264 + (i * 16 + m16) * 8]);

    // l-accumulate via ones-MFMA: lacc rows == oacc rows (C-layout).
#pragma unroll
    for (int i = 0; i < 2; ++i) {
      lacc[i] = __builtin_amdgcn_mfma_f32_16x16x32_bf16(pf[i][0], ones, lacc[i], 0, 0, 0);
      lacc[i] = __builtin_amdgcn_mfma_f32_16x16x32_bf16(pf[i][1], ones, lacc[i], 0, 0, 0);
    }

#pragma unroll
    for (int j = 0; j < 4; ++j) {
      bf16x8 vf0 = *reinterpret_cast<const bf16x8*>(
          &Vs[(0 * 4 + quad) * 512 + (j * 16 + m16) * 8]);
      bf16x8 vf1 = *reinterpret_cast<const bf16x8*>(
          &Vs[(1 * 4 + quad) * 512 + (j * 16 + m16) * 8]);
#pragma unroll
      for (int i = 0; i < 2; ++i) {
        oacc[i][j] = __builtin_amdgcn_mfma_f32_16x16x32_bf16(pf[i][0], vf0, oacc[i][j], 0, 0, 0);
        oacc[i][j] = __builtin_amdgcn_mfma_f32_16x16x32_bf16(pf[i][1], vf1, oacc[i][j], 0, 0, 0);
      }
    }
    __syncthreads();
  }

#pragma unroll
  for (int i = 0; i < 2; ++i)
#pragma unroll
    for (int j = 0; j < 4; ++j) {
      int d = j * 16 + m16;
#pragma unroll
      for (int rg = 0; rg < 4; ++rg) {
        int ql = qb * 128 + w * 32 + i * 16 + quad * 4 + rg;
        Out[(b * kL + ql) * kE + h * kHD + d] =
            f2bf(oacc[i][j][rg] / lacc[i][rg]);
      }
    }
}

extern "C" void kernel_launch(void* const* d_in, const int* in_sizes, int n_in,
                              void* d_out, int out_size, void* d_ws, size_t ws_size,
                              hipStream_t stream) {
  const float* x  = (const float*)d_in[0];
  const int* mask = (const int*)d_in[1];
  const float* Wq = (const float*)d_in[2];
  const float* bq = (const float*)d_in[3];
  const float* Wk = (const float*)d_in[4];
  const float* bk = (const float*)d_in[5];
  const float* Wv = (const float*)d_in[6];
  const float* bv = (const float*)d_in[7];
  const float* Wo = (const float*)d_in[8];
  const float* bo = (const float*)d_in[9];

  short* ws  = (short*)d_ws;
  short* xb  = ws;                  // 8388608 shorts
  short* Wqb = xb  + 8388608;       // 4 x 1048576, contiguous
  short* Wkb = Wqb + 1048576;
  short* Wvb = Wkb + 1048576;
  short* Wob = Wvb + 1048576;
  short* Qb  = Wob + 1048576;       // 8388608 each
  short* Kb  = Qb  + 8388608;
  short* Vtb = Kb  + 8388608;
  short* AOb = Vtb + 8388608;       // doubles as Vl before attention runs
  float* Mkf = (float*)(AOb + 8388608);  // 8192 floats

  k_cvt<<<8192, 256, 0, stream>>>(x, xb, 8388608);
  k_cvtw<<<4128, 256, 0, stream>>>(Wq, Wk, Wv, Wo, mask, Wqb, Mkf);

  // V row-major into AOb (dead until attention), then transpose into Vtb.
  k_gemm_qkv<<<dim3(24, 64), 256, 0, stream>>>(xb, Wqb, Wkb, Wvb, bq, bk, bv, Qb, Kb, AOb);
  k_trv<<<dim3(32, 64), 256, 0, stream>>>(AOb, Vtb);
  k_attn<<<dim3(16, 64), 256, 0, stream>>>(Qb, Kb, Vtb, Mkf, AOb);
  k_gemm_out<<<dim3(8, 64), 256, 0, stream>>>(AOb, Wob, bo, (float*)d_out);
}